// Round 1
// 855.578 us; speedup vs baseline: 1.1358x; 1.1358x over previous
//
#include <hip/hip_runtime.h>
#include <stdint.h>

#define F8_MAX 448.0f

typedef int   intx4   __attribute__((ext_vector_type(4)));
typedef int   intx8   __attribute__((ext_vector_type(8)));
typedef float floatx16 __attribute__((ext_vector_type(16)));

// ---------------------------------------------------------------- helpers
__device__ __forceinline__ void gld16(const void* g, void* l) {
  // async global->LDS, 16B per lane; LDS dst is wave-uniform base + lane*16
  __builtin_amdgcn_global_load_lds(
      (const __attribute__((address_space(1))) unsigned int*)g,
      (__attribute__((address_space(3))) unsigned int*)l,
      16, 0, 0);
}

// ---------------------------------------------------------------- amax (2-stage, NO atomics)
// Stage 1: per-block max via wave shuffle + LDS, plain store to partial[].
// Stage 2: single block reduces the partials. Removes the 16K same-address
// device-scope atomicMax ops (cross-XCD serialization suspect).
__global__ void amax_partial(const float4* __restrict__ x, long n4,
                             float* __restrict__ partial) {
  long idx = (long)blockIdx.x * blockDim.x + threadIdx.x;
  long stride = (long)gridDim.x * blockDim.x;
  float m = 0.f;
  for (long i = idx; i < n4; i += stride) {
    float4 v = x[i];
    m = fmaxf(m, fmaxf(fmaxf(fabsf(v.x), fabsf(v.y)),
                       fmaxf(fabsf(v.z), fabsf(v.w))));
  }
  #pragma unroll
  for (int off = 32; off > 0; off >>= 1)
    m = fmaxf(m, __shfl_down(m, off, 64));
  __shared__ float wmax[4];
  const int wave = threadIdx.x >> 6;
  const int lane = threadIdx.x & 63;
  if (lane == 0) wmax[wave] = m;
  __syncthreads();
  if (threadIdx.x == 0)
    partial[blockIdx.x] =
        fmaxf(fmaxf(wmax[0], wmax[1]), fmaxf(wmax[2], wmax[3]));
}

__global__ void amax_final(const float* __restrict__ partial, int n,
                           unsigned* __restrict__ amax_bits) {
  float m = 0.f;
  for (int i = threadIdx.x; i < n; i += blockDim.x) m = fmaxf(m, partial[i]);
  #pragma unroll
  for (int off = 32; off > 0; off >>= 1)
    m = fmaxf(m, __shfl_down(m, off, 64));
  __shared__ float wmax[16];
  const int wave = threadIdx.x >> 6;
  const int lane = threadIdx.x & 63;
  if (lane == 0) wmax[wave] = m;
  __syncthreads();
  if (threadIdx.x == 0) {
    float r = 0.f;
    const int nw = (int)(blockDim.x >> 6);
    for (int i = 0; i < nw; i++) r = fmaxf(r, wmax[i]);
    *amax_bits = __float_as_uint(r);
  }
}

// ---------------------------------------------------------------- quantize x -> fp8
__global__ void quant_x(const float4* __restrict__ x, unsigned* __restrict__ q,
                        const unsigned* __restrict__ amax_bits, long n4) {
  long i = (long)blockIdx.x * blockDim.x + threadIdx.x;
  if (i >= n4) return;
  float amax = fmaxf(__uint_as_float(*amax_bits), 1e-12f);
  float s = F8_MAX / amax;            // same fp32 division as reference
  float4 v = x[i];
  float a = fminf(fmaxf(v.x * s, -F8_MAX), F8_MAX);
  float b = fminf(fmaxf(v.y * s, -F8_MAX), F8_MAX);
  float c = fminf(fmaxf(v.z * s, -F8_MAX), F8_MAX);
  float d = fminf(fmaxf(v.w * s, -F8_MAX), F8_MAX);
  int w = 0;
  w = __builtin_amdgcn_cvt_pk_fp8_f32(a, b, w, false);  // bytes 0,1
  w = __builtin_amdgcn_cvt_pk_fp8_f32(c, d, w, true);   // bytes 2,3
  q[i] = (unsigned)w;
}

// ---------------------------------------------------------------- qweight f32 -> fp8 bytes
__global__ void quant_w(const float4* __restrict__ x, unsigned* __restrict__ q, long n4) {
  long i = (long)blockIdx.x * blockDim.x + threadIdx.x;
  if (i >= n4) return;
  float4 v = x[i];
  int w = 0;
  w = __builtin_amdgcn_cvt_pk_fp8_f32(v.x, v.y, w, false);
  w = __builtin_amdgcn_cvt_pk_fp8_f32(v.z, v.w, w, true);
  q[i] = (unsigned)w;
}

// ---------------------------------------------------------------- GEMM
// C[m][n] = sum_k A[m][k]*B[n][k]; A:[M][K] fp8, B:[N][K] fp8
// 128x128 tile, BK=64, 4 waves (2x2 of 64x64), each wave 2x2 of
// mfma_scale_f32_32x32x64_f8f6f4 with unit scales (== plain fp8 matmul, 2x rate).
//
// LDS layout: Asm[row][64B] with XOR slot swizzle: the 16B chunk c (k-bytes
// [c*16, c*16+16)) of row r lives at slot s = c ^ ((r>>1)&3). A wave-wide
// ds_read_b128 then touches all 8 128B-slots with 8 dwords/bank (the b128
// minimum -> no conflicts). Staging inverts the swizzle in the global src
// address; 4 lanes cover one row's 64B contiguously (coalesced).
#define BM 128
#define BN 128
#define BK 64

__global__ __launch_bounds__(256) void gemm_fp8(
    const uint8_t* __restrict__ A, const uint8_t* __restrict__ B,
    float* __restrict__ C, const float* __restrict__ bias,
    const unsigned* __restrict__ amax_bits, const float* __restrict__ w_scale,
    int M, int N, int K) {
  __shared__ uint8_t Asm[BM][BK];
  __shared__ uint8_t Bsm[BN][BK];

  const int tid = threadIdx.x;
  const int wave = tid >> 6;
  const int lane = tid & 63;
  const int m_block = blockIdx.y * BM;
  const int n_block = blockIdx.x * BN;
  const int wm = (wave >> 1) * 64;   // wave's 64x64 subtile
  const int wn = (wave & 1) * 64;
  const int r32 = lane & 31;         // row/col within a 32-tile
  const int khalf = lane >> 5;       // which 32-wide k-half this lane holds

  floatx16 acc[2][2] = {};
  const long Kl = K;

  // staging: lane -> (row-in-segment, chunk). seg*8 == 0 mod 4, so the swizzle
  // term reduces to lane bits only.
  const int st_row = lane >> 2;                        // 0..15
  const int st_c   = (lane & 3) ^ ((lane >> 3) & 3);   // global chunk for this slot
  const int sw     = (r32 >> 1) & 3;                   // fragment-read swizzle

  for (int k0 = 0; k0 < K; k0 += BK) {
    #pragma unroll
    for (int t = 0; t < 4; t++) {
      int id  = wave * 4 + t;   // 0..15 wave-instructions of 1KB
      int isB = id >> 3;
      int seg = id & 7;         // 16-row segment
      int row = seg * 16 + st_row;
      const uint8_t* gsrc = (isB ? B + (long)(n_block + row) * Kl
                                 : A + (long)(m_block + row) * Kl)
                            + k0 + st_c * 16;
      void* ldst = isB ? (void*)&Bsm[seg * 16][0] : (void*)&Asm[seg * 16][0];
      gld16(gsrc, ldst);
    }
    __syncthreads();

    intx8 a_frag[2], b_frag[2];
    #pragma unroll
    for (int mi = 0; mi < 2; mi++) {
      int r  = wm + mi * 32 + r32;
      int s1 = (khalf * 2) ^ sw;
      intx4 lo = *(const intx4*)&Asm[r][s1 * 16];        // k [khalf*32, +16)
      intx4 hi = *(const intx4*)&Asm[r][(s1 ^ 1) * 16];  // k [khalf*32+16, +16)
      a_frag[mi] = intx8{lo.x, lo.y, lo.z, lo.w, hi.x, hi.y, hi.z, hi.w};
    }
    #pragma unroll
    for (int ni = 0; ni < 2; ni++) {
      int r  = wn + ni * 32 + r32;
      int s1 = (khalf * 2) ^ sw;
      intx4 lo = *(const intx4*)&Bsm[r][s1 * 16];
      intx4 hi = *(const intx4*)&Bsm[r][(s1 ^ 1) * 16];
      b_frag[ni] = intx8{lo.x, lo.y, lo.z, lo.w, hi.x, hi.y, hi.z, hi.w};
    }

    #pragma unroll
    for (int mi = 0; mi < 2; mi++)
      #pragma unroll
      for (int ni = 0; ni < 2; ni++)
        acc[mi][ni] = __builtin_amdgcn_mfma_scale_f32_32x32x64_f8f6f4(
            a_frag[mi], b_frag[ni], acc[mi][ni],
            0, 0,                     // cbsz=fp8(e4m3), blgp=fp8(e4m3)
            0, 0x7F7F7F7F,            // A scales: E8M0 127 == x1.0
            0, 0x7F7F7F7F);           // B scales: x1.0
    __syncthreads();
  }

  // ---- epilogue: out = acc * (x_scale * w_scale) + bias ----
  float amax  = fmaxf(__uint_as_float(*amax_bits), 1e-12f);
  float sq    = F8_MAX / amax;   // reference: s = 448/amax
  float xs    = 1.0f / sq;       // reference: x_scale = 1/s (two divisions, kept)
  float scale = xs * w_scale[0];
  #pragma unroll
  for (int ni = 0; ni < 2; ni++) {
    int col = n_block + wn + ni * 32 + r32;   // 32x32 C/D: col = lane&31
    float bz = bias[col];
    #pragma unroll
    for (int mi = 0; mi < 2; mi++) {
      #pragma unroll
      for (int r = 0; r < 16; r++) {
        // 32x32 C/D: row = (reg&3) + 8*(reg>>2) + 4*(lane>>5)
        int row = m_block + wm + mi * 32 + (r & 3) + 8 * (r >> 2) + 4 * khalf;
        C[(long)row * N + col] = acc[mi][ni][r] * scale + bz;
      }
    }
  }
}

// ---------------------------------------------------------------- launch
extern "C" void kernel_launch(void* const* d_in, const int* in_sizes, int n_in,
                              void* d_out, int out_size, void* d_ws, size_t ws_size,
                              hipStream_t stream) {
  const float* x       = (const float*)d_in[0];
  const float* qw      = (const float*)d_in[1];
  const float* w_scale = (const float*)d_in[2];
  const float* bias    = (const float*)d_in[3];
  const long xN = in_sizes[0];         // M*K
  const long wN = in_sizes[1];         // N*K
  const int  N  = in_sizes[3];
  const int  K  = (int)(wN / N);
  const int  M  = (int)(xN / K);

  unsigned* amax_bits = (unsigned*)d_ws;
  uint8_t*  qx  = (uint8_t*)d_ws + 256;        // M*K fp8 bytes
  uint8_t*  qwq = qx + xN;                     // N*K fp8 bytes
  float*    out = (float*)d_out;

  // Stage-1 partials live in the qx region: consumed by amax_final BEFORE
  // quant_x overwrites qx (stream-serial), so no extra workspace needed.
  float* partial = (float*)qx;
  const int AMAX_BLOCKS = 4096;

  amax_partial<<<AMAX_BLOCKS, 256, 0, stream>>>((const float4*)x, xN / 4, partial);
  amax_final<<<1, 1024, 0, stream>>>(partial, AMAX_BLOCKS, amax_bits);
  quant_x<<<(unsigned)((xN / 4 + 255) / 256), 256, 0, stream>>>(
      (const float4*)x, (unsigned*)qx, amax_bits, xN / 4);
  quant_w<<<(unsigned)((wN / 4 + 255) / 256), 256, 0, stream>>>(
      (const float4*)qw, (unsigned*)qwq, wN / 4);

  dim3 grid(N / BN, M / BM);
  gemm_fp8<<<grid, 256, 0, stream>>>(qx, qwq, out, bias, amax_bits, w_scale, M, N, K);
}

// Round 2
// 841.848 us; speedup vs baseline: 1.1543x; 1.0163x over previous
//
#include <hip/hip_runtime.h>
#include <stdint.h>

#define F8_MAX 448.0f

typedef int   intx4   __attribute__((ext_vector_type(4)));
typedef int   intx8   __attribute__((ext_vector_type(8)));
typedef float floatx16 __attribute__((ext_vector_type(16)));

// ---------------------------------------------------------------- helpers
__device__ __forceinline__ void gld16(const void* g, void* l) {
  // async global->LDS, 16B per lane; LDS dst is wave-uniform base + lane*16
  __builtin_amdgcn_global_load_lds(
      (const __attribute__((address_space(1))) unsigned int*)g,
      (__attribute__((address_space(3))) unsigned int*)l,
      16, 0, 0);
}

__device__ __forceinline__ float amax4(float4 v) {
  return fmaxf(fmaxf(fabsf(v.x), fabsf(v.y)), fmaxf(fabsf(v.z), fabsf(v.w)));
}

__device__ __forceinline__ unsigned pk8(float4 v, float s) {
  float a = fminf(fmaxf(v.x * s, -F8_MAX), F8_MAX);
  float b = fminf(fmaxf(v.y * s, -F8_MAX), F8_MAX);
  float c = fminf(fmaxf(v.z * s, -F8_MAX), F8_MAX);
  float d = fminf(fmaxf(v.w * s, -F8_MAX), F8_MAX);
  int w = 0;
  w = __builtin_amdgcn_cvt_pk_fp8_f32(a, b, w, false);  // bytes 0,1
  w = __builtin_amdgcn_cvt_pk_fp8_f32(c, d, w, true);   // bytes 2,3
  return (unsigned)w;
}

// ---------------------------------------------------------------- amax (2-stage, no atomics)
// Grid-stride, fully-resident grid (2048 blk x 4 waves = 8192 wave slots),
// 64B/lane/iter: 4 independent b128 loads in flight per iteration.
__global__ __launch_bounds__(256) void amax_partial(
    const float4* __restrict__ x, long n16, float* __restrict__ partial) {
  long idx = (long)blockIdx.x * blockDim.x + threadIdx.x;
  long stride = (long)gridDim.x * blockDim.x;
  float m = 0.f;
  for (long i = idx; i < n16; i += stride) {
    const float4* p = x + i * 4;
    float4 v0 = p[0], v1 = p[1], v2 = p[2], v3 = p[3];
    m = fmaxf(m, fmaxf(fmaxf(amax4(v0), amax4(v1)),
                       fmaxf(amax4(v2), amax4(v3))));
  }
  #pragma unroll
  for (int off = 32; off > 0; off >>= 1)
    m = fmaxf(m, __shfl_down(m, off, 64));
  __shared__ float wmax[4];
  const int wave = threadIdx.x >> 6;
  const int lane = threadIdx.x & 63;
  if (lane == 0) wmax[wave] = m;
  __syncthreads();
  if (threadIdx.x == 0)
    partial[blockIdx.x] =
        fmaxf(fmaxf(wmax[0], wmax[1]), fmaxf(wmax[2], wmax[3]));
}

__global__ void amax_final(const float* __restrict__ partial, int n,
                           unsigned* __restrict__ amax_bits) {
  float m = 0.f;
  for (int i = threadIdx.x; i < n; i += blockDim.x) m = fmaxf(m, partial[i]);
  #pragma unroll
  for (int off = 32; off > 0; off >>= 1)
    m = fmaxf(m, __shfl_down(m, off, 64));
  __shared__ float wmax[16];
  const int wave = threadIdx.x >> 6;
  const int lane = threadIdx.x & 63;
  if (lane == 0) wmax[wave] = m;
  __syncthreads();
  if (threadIdx.x == 0) {
    float r = 0.f;
    const int nw = (int)(blockDim.x >> 6);
    for (int i = 0; i < nw; i++) r = fmaxf(r, wmax[i]);
    *amax_bits = __float_as_uint(r);
  }
}

// ---------------------------------------------------------------- quantize x -> fp8
// Grid-stride resident grid (G11), 16 floats/lane/iter: 4x b128 load + 1x
// dwordx4 store. Scale hoisted out of the loop.
__global__ __launch_bounds__(256) void quant_x(
    const float4* __restrict__ x, intx4* __restrict__ q,
    const unsigned* __restrict__ amax_bits, long n16) {
  float amax = fmaxf(__uint_as_float(*amax_bits), 1e-12f);
  float s = F8_MAX / amax;            // same fp32 division as reference
  long idx = (long)blockIdx.x * blockDim.x + threadIdx.x;
  long stride = (long)gridDim.x * blockDim.x;
  for (long i = idx; i < n16; i += stride) {
    const float4* p = x + i * 4;
    float4 v0 = p[0], v1 = p[1], v2 = p[2], v3 = p[3];
    intx4 o;
    o.x = (int)pk8(v0, s);
    o.y = (int)pk8(v1, s);
    o.z = (int)pk8(v2, s);
    o.w = (int)pk8(v3, s);
    q[i] = o;
  }
}

// ---------------------------------------------------------------- qweight f32 -> fp8 bytes
__global__ __launch_bounds__(256) void quant_w(
    const float4* __restrict__ x, intx4* __restrict__ q, long n16) {
  long idx = (long)blockIdx.x * blockDim.x + threadIdx.x;
  long stride = (long)gridDim.x * blockDim.x;
  for (long i = idx; i < n16; i += stride) {
    const float4* p = x + i * 4;
    float4 v0 = p[0], v1 = p[1], v2 = p[2], v3 = p[3];
    intx4 o;
    o.x = (int)pk8(v0, 1.0f);
    o.y = (int)pk8(v1, 1.0f);
    o.z = (int)pk8(v2, 1.0f);
    o.w = (int)pk8(v3, 1.0f);
    q[i] = o;
  }
}

// ---------------------------------------------------------------- GEMM
// C[m][n] = sum_k A[m][k]*B[n][k]; A:[M][K] fp8, B:[N][K] fp8
// 128x128 tile, BK=64, 4 waves (2x2 of 64x64), each wave 2x2 of
// mfma_scale_f32_32x32x64_f8f6f4 with unit scales (== plain fp8 matmul, 2x rate).
//
// LDS layout: Asm[row][64B] with XOR slot swizzle: the 16B chunk c (k-bytes
// [c*16, c*16+16)) of row r lives at slot s = c ^ ((r>>1)&3). A wave-wide
// ds_read_b128 then touches all 8 128B-slots with 8 dwords/bank (the b128
// minimum -> no conflicts). Staging inverts the swizzle in the global src
// address; 4 lanes cover one row's 64B contiguously (coalesced).
#define BM 128
#define BN 128
#define BK 64

__global__ __launch_bounds__(256) void gemm_fp8(
    const uint8_t* __restrict__ A, const uint8_t* __restrict__ B,
    float* __restrict__ C, const float* __restrict__ bias,
    const unsigned* __restrict__ amax_bits, const float* __restrict__ w_scale,
    int M, int N, int K) {
  __shared__ uint8_t Asm[BM][BK];
  __shared__ uint8_t Bsm[BN][BK];

  const int tid = threadIdx.x;
  const int wave = tid >> 6;
  const int lane = tid & 63;
  const int m_block = blockIdx.y * BM;
  const int n_block = blockIdx.x * BN;
  const int wm = (wave >> 1) * 64;   // wave's 64x64 subtile
  const int wn = (wave & 1) * 64;
  const int r32 = lane & 31;         // row/col within a 32-tile
  const int khalf = lane >> 5;       // which 32-wide k-half this lane holds

  floatx16 acc[2][2] = {};
  const long Kl = K;

  // staging: lane -> (row-in-segment, chunk). seg*8 == 0 mod 4, so the swizzle
  // term reduces to lane bits only.
  const int st_row = lane >> 2;                        // 0..15
  const int st_c   = (lane & 3) ^ ((lane >> 3) & 3);   // global chunk for this slot
  const int sw     = (r32 >> 1) & 3;                   // fragment-read swizzle

  for (int k0 = 0; k0 < K; k0 += BK) {
    #pragma unroll
    for (int t = 0; t < 4; t++) {
      int id  = wave * 4 + t;   // 0..15 wave-instructions of 1KB
      int isB = id >> 3;
      int seg = id & 7;         // 16-row segment
      int row = seg * 16 + st_row;
      const uint8_t* gsrc = (isB ? B + (long)(n_block + row) * Kl
                                 : A + (long)(m_block + row) * Kl)
                            + k0 + st_c * 16;
      void* ldst = isB ? (void*)&Bsm[seg * 16][0] : (void*)&Asm[seg * 16][0];
      gld16(gsrc, ldst);
    }
    __syncthreads();

    intx8 a_frag[2], b_frag[2];
    #pragma unroll
    for (int mi = 0; mi < 2; mi++) {
      int r  = wm + mi * 32 + r32;
      int s1 = (khalf * 2) ^ sw;
      intx4 lo = *(const intx4*)&Asm[r][s1 * 16];        // k [khalf*32, +16)
      intx4 hi = *(const intx4*)&Asm[r][(s1 ^ 1) * 16];  // k [khalf*32+16, +16)
      a_frag[mi] = intx8{lo.x, lo.y, lo.z, lo.w, hi.x, hi.y, hi.z, hi.w};
    }
    #pragma unroll
    for (int ni = 0; ni < 2; ni++) {
      int r  = wn + ni * 32 + r32;
      int s1 = (khalf * 2) ^ sw;
      intx4 lo = *(const intx4*)&Bsm[r][s1 * 16];
      intx4 hi = *(const intx4*)&Bsm[r][(s1 ^ 1) * 16];
      b_frag[ni] = intx8{lo.x, lo.y, lo.z, lo.w, hi.x, hi.y, hi.z, hi.w};
    }

    #pragma unroll
    for (int mi = 0; mi < 2; mi++)
      #pragma unroll
      for (int ni = 0; ni < 2; ni++)
        acc[mi][ni] = __builtin_amdgcn_mfma_scale_f32_32x32x64_f8f6f4(
            a_frag[mi], b_frag[ni], acc[mi][ni],
            0, 0,                     // cbsz=fp8(e4m3), blgp=fp8(e4m3)
            0, 0x7F7F7F7F,            // A scales: E8M0 127 == x1.0
            0, 0x7F7F7F7F);           // B scales: x1.0
    __syncthreads();
  }

  // ---- epilogue: out = acc * (x_scale * w_scale) + bias ----
  float amax  = fmaxf(__uint_as_float(*amax_bits), 1e-12f);
  float sq    = F8_MAX / amax;   // reference: s = 448/amax
  float xs    = 1.0f / sq;       // reference: x_scale = 1/s (two divisions, kept)
  float scale = xs * w_scale[0];
  #pragma unroll
  for (int ni = 0; ni < 2; ni++) {
    int col = n_block + wn + ni * 32 + r32;   // 32x32 C/D: col = lane&31
    float bz = bias[col];
    #pragma unroll
    for (int mi = 0; mi < 2; mi++) {
      #pragma unroll
      for (int r = 0; r < 16; r++) {
        // 32x32 C/D: row = (reg&3) + 8*(reg>>2) + 4*(lane>>5)
        int row = m_block + wm + mi * 32 + (r & 3) + 8 * (r >> 2) + 4 * khalf;
        C[(long)row * N + col] = acc[mi][ni][r] * scale + bz;
      }
    }
  }
}

// ---------------------------------------------------------------- launch
extern "C" void kernel_launch(void* const* d_in, const int* in_sizes, int n_in,
                              void* d_out, int out_size, void* d_ws, size_t ws_size,
                              hipStream_t stream) {
  const float* x       = (const float*)d_in[0];
  const float* qw      = (const float*)d_in[1];
  const float* w_scale = (const float*)d_in[2];
  const float* bias    = (const float*)d_in[3];
  const long xN = in_sizes[0];         // M*K
  const long wN = in_sizes[1];         // N*K
  const int  N  = in_sizes[3];
  const int  K  = (int)(wN / N);
  const int  M  = (int)(xN / K);

  unsigned* amax_bits = (unsigned*)d_ws;
  uint8_t*  qx  = (uint8_t*)d_ws + 256;        // M*K fp8 bytes
  uint8_t*  qwq = qx + xN;                     // N*K fp8 bytes
  float*    out = (float*)d_out;

  // Stage-1 partials live in the qx region: consumed by amax_final BEFORE
  // quant_x overwrites qx (stream-serial), so no extra workspace needed.
  float* partial = (float*)qx;
  // 2048 blocks x 4 waves = 8192 waves = exactly full residency on 256 CUs
  // (G11: cap the grid, grid-stride the rest).
  const int PBLK = 2048;

  // sizes here are multiples of 16 floats (M,K,N powers of two); the /16
  // vector kernels rely on that.
  amax_partial<<<PBLK, 256, 0, stream>>>((const float4*)x, xN / 16, partial);
  amax_final<<<1, 1024, 0, stream>>>(partial, PBLK, amax_bits);
  quant_x<<<PBLK, 256, 0, stream>>>((const float4*)x, (intx4*)qx, amax_bits, xN / 16);
  quant_w<<<PBLK, 256, 0, stream>>>((const float4*)qw, (intx4*)qwq, wN / 16);

  dim3 grid(N / BN, M / BM);
  gemm_fp8<<<grid, 256, 0, stream>>>(qx, qwq, out, bias, amax_bits, w_scale, M, N, K);
}